// Round 1
// baseline (361.942 us; speedup 1.0000x reference)
//
#include <hip/hip_runtime.h>

typedef __attribute__((ext_vector_type(4))) float f32x4;
typedef __attribute__((ext_vector_type(16))) float f32x16;
typedef __attribute__((ext_vector_type(8))) _Float16 f16x8;
typedef __attribute__((ext_vector_type(4))) _Float16 f16x4;

__device__ __forceinline__ void gload_lds16(const void* g, void* l) {
  __builtin_amdgcn_global_load_lds((__attribute__((address_space(1))) void*)(g),
                                   (__attribute__((address_space(3))) void*)(l), 16, 0, 0);
}

#define SB0() __builtin_amdgcn_sched_barrier(0)
#define WAITV6() asm volatile("s_waitcnt vmcnt(6)" ::: "memory")
#define WAITV0() asm volatile("s_waitcnt vmcnt(0)" ::: "memory")

// ---- fused prep: cast H fp32->fp16 (blocks 0..8191) + weight transpose-cast
// (blocks 8192..12287, mapping the old (32,32,4) wtrans grid) ----
__global__ __launch_bounds__(256) void prep(const float* __restrict__ Hs,
                                            const float* __restrict__ W0, const float* __restrict__ W1,
                                            const float* __restrict__ W2, const float* __restrict__ W3,
                                            _Float16* __restrict__ Hb, _Float16* __restrict__ Wt) {
  __shared__ _Float16 tile[64][65];
  const int bid = blockIdx.x, tid = threadIdx.x;
  if (bid < 8192) {
    int i = (bid * 256 + tid) * 4;
    float4 v = *(const float4*)(Hs + i);
    f16x4 o = { (_Float16)v.x, (_Float16)v.y, (_Float16)v.z, (_Float16)v.w };
    *(f16x4*)(Hb + i) = o;
    return;
  }
  const int t = bid - 8192;
  const int z = t >> 10, k0 = ((t >> 5) & 31) * 64, n0 = (t & 31) * 64;
  const float* W = z == 0 ? W0 : z == 1 ? W1 : z == 2 ? W2 : W3;
  _Float16* Wo_ = Wt + (size_t)z * (2048u * 2048u);
  #pragma unroll
  for (int p = 0; p < 4; ++p) {
    int o = p * 256 + tid, r = o >> 4, c = o & 15;
    float4 v = *(const float4*)(W + (size_t)(k0 + r) * 2048 + n0 + c * 4);
    tile[r][c * 4 + 0] = (_Float16)v.x;
    tile[r][c * 4 + 1] = (_Float16)v.y;
    tile[r][c * 4 + 2] = (_Float16)v.z;
    tile[r][c * 4 + 3] = (_Float16)v.w;
  }
  __syncthreads();
  #pragma unroll
  for (int p = 0; p < 2; ++p) {
    int o = p * 256 + tid, nl = o >> 3, c = o & 7;
    f16x8 u;
    #pragma unroll
    for (int i = 0; i < 8; ++i) u[i] = tile[c * 8 + i][nl];
    *(f16x8*)(Wo_ + (size_t)(n0 + nl) * 2048 + k0 + c * 8) = u;
  }
}

// ---- generic big-tile GEMM tile (serial schedule) — still used by gemm_wo ----
template <int SM, int SN, typename OutT>
__device__ __forceinline__ void gemm_tile(const _Float16* __restrict__ A,
                                          const _Float16* __restrict__ Bt,
                                          OutT* __restrict__ C,
                                          int K, int N, int m0, int n0, _Float16* S) {
  _Float16* As = S;                    // (SM*64) x 64
  _Float16* Bs = S + SM * 64 * 64;     // (SN*64) x 64
  const int tid = threadIdx.x;
  const int lane = tid & 63, w = tid >> 6, l32 = lane & 31, half = lane >> 5;
  const int wm = (w & 1) * SM * 32, wn = (w >> 1) * SN * 32;
  f32x16 acc[SM][SN];
  #pragma unroll
  for (int s = 0; s < SM; ++s)
    #pragma unroll
    for (int t = 0; t < SN; ++t) acc[s][t] = 0;

  for (int k0 = 0; k0 < K; k0 += 64) {
    __syncthreads();
    #pragma unroll
    for (int p = 0; p < SM * 2; ++p) {
      int o = p * 256 + tid, r = o >> 3, c = o & 7;
      gload_lds16(A + (size_t)(m0 + r) * K + k0 + ((c ^ (r & 7)) * 8), (char*)As + o * 16);
    }
    #pragma unroll
    for (int p = 0; p < SN * 2; ++p) {
      int o = p * 256 + tid, r = o >> 3, c = o & 7;
      gload_lds16(Bt + (size_t)(n0 + r) * K + k0 + ((c ^ (r & 7)) * 8), (char*)Bs + o * 16);
    }
    __builtin_amdgcn_s_waitcnt(0);
    __syncthreads();
    #pragma unroll
    for (int kk = 0; kk < 4; ++kk) {
      const int slot = ((2 * kk + half) ^ (l32 & 7)) * 8;
      f16x8 af[SM], bf[SN];
      #pragma unroll
      for (int s = 0; s < SM; ++s) af[s] = *(const f16x8*)(As + (wm + s * 32 + l32) * 64 + slot);
      #pragma unroll
      for (int t = 0; t < SN; ++t) bf[t] = *(const f16x8*)(Bs + (wn + t * 32 + l32) * 64 + slot);
      #pragma unroll
      for (int s = 0; s < SM; ++s)
        #pragma unroll
        for (int t = 0; t < SN; ++t)
          acc[s][t] = __builtin_amdgcn_mfma_f32_32x32x16_f16(bf[t], af[s], acc[s][t], 0, 0, 0);
    }
  }
  #pragma unroll
  for (int s = 0; s < SM; ++s) {
    const size_t row = (size_t)(m0 + wm + s * 32 + l32);
    #pragma unroll
    for (int t = 0; t < SN; ++t) {
      #pragma unroll
      for (int g = 0; g < 4; ++g) {
        const int col = n0 + wn + t * 32 + g * 8 + 4 * half;
        if constexpr (sizeof(OutT) == 2) {
          f16x4 o = { (_Float16)acc[s][t][4 * g + 0], (_Float16)acc[s][t][4 * g + 1],
                      (_Float16)acc[s][t][4 * g + 2], (_Float16)acc[s][t][4 * g + 3] };
          *(f16x4*)((_Float16*)C + row * N + col) = o;
        } else {
          f32x4 o = { acc[s][t][4 * g + 0], acc[s][t][4 * g + 1],
                      acc[s][t][4 * g + 2], acc[s][t][4 * g + 3] };
          *(f32x4*)((float*)C + row * N + col) = o;
        }
      }
    }
  }
}

// ---- 8-phase pipelined 256x256 GEMM (T2 swizzle + T3/T4 counted vmcnt + T5 setprio).
// K fixed = 2048 (32 K-tiles of BK=64). 512 threads = 8 waves (2M x 4N), wave tile 128x64.
// LDS: 2 x (A 256x64 + B 256x64) f16 = 128 KB double buffer.
// Staging pipeline: each phase issues 2 global_load_lds (one 64-row chunk each);
//   ph0(t): tile t+1 A[64..127],A[192..255] -> other buffer (completing tile t+1)
//   ph1(t): tile t+2 A[0..63],A[128..191]   -> current buffer (read finished at ph0)
//   ph2(t): tile t+2 B[0..127]              -> current buffer (B read finished at ph1)
//   ph3(t): tile t+2 B[128..255], then vmcnt(6): leaves exactly tile t+2's 6 chunks
//           in flight => tile t+1 fully landed before its first ds_read.
// Tail uses vmcnt(0) (prefetch suppressed would otherwise under-count).
__device__ __forceinline__ void gemm256(const _Float16* __restrict__ A,
                                        const _Float16* __restrict__ Bt,
                                        _Float16* __restrict__ C, int ldc,
                                        int m0, int n0, _Float16* S) {
  _Float16* const As0 = S;
  _Float16* const As1 = S + 16384;
  _Float16* const Bs0 = S + 32768;
  _Float16* const Bs1 = S + 49152;
  const int tid = (int)threadIdx.x;
  const int lane = tid & 63, w = tid >> 6, l32 = lane & 31, half = lane >> 5;
  const int wm = (w & 1) * 128, wn = (w >> 1) * 64;

  f32x16 acc[4][2];
  #pragma unroll
  for (int s = 0; s < 4; ++s)
    #pragma unroll
    for (int t = 0; t < 2; ++t) acc[s][t] = 0;

  f16x8 af[2][4];   // current m-pair fragments (pair0: rows wm..wm+63, pair1: wm+64..wm+127)
  f16x8 bf[2][4];   // both n-frags, live across the whole K-tile

  auto stageA = [&](_Float16* dst, int ar, int kt) {
    const int r = tid >> 3, c = tid & 7;
    gload_lds16(A + (size_t)(m0 + ar + r) * 2048 + kt * 64 + ((c ^ (r & 7)) << 3),
                (char*)dst + ar * 128 + tid * 16);
  };
  auto stageB = [&](_Float16* dst, int br, int kt) {
    const int r = tid >> 3, c = tid & 7;
    gload_lds16(Bt + (size_t)(n0 + br + r) * 2048 + kt * 64 + ((c ^ (r & 7)) << 3),
                (char*)dst + br * 128 + tid * 16);
  };
  auto ldA = [&](const _Float16* as, int p) {
    #pragma unroll
    for (int s2 = 0; s2 < 2; ++s2)
      #pragma unroll
      for (int kk = 0; kk < 4; ++kk)
        af[s2][kk] = *(const f16x8*)(as + (wm + p * 64 + s2 * 32 + l32) * 64 +
                                     (((2 * kk + half) ^ (l32 & 7)) << 3));
  };
  auto ldB = [&](const _Float16* bs, int q) {
    #pragma unroll
    for (int kk = 0; kk < 4; ++kk)
      bf[q][kk] = *(const f16x8*)(bs + (wn + q * 32 + l32) * 64 +
                                  (((2 * kk + half) ^ (l32 & 7)) << 3));
  };
  auto mm = [&](int sp, int q) {
    __builtin_amdgcn_s_setprio(1);
    #pragma unroll
    for (int kk = 0; kk < 4; ++kk)
      #pragma unroll
      for (int s2 = 0; s2 < 2; ++s2)
        acc[sp * 2 + s2][q] = __builtin_amdgcn_mfma_f32_32x32x16_f16(
            bf[q][kk], af[s2][kk], acc[sp * 2 + s2][q], 0, 0, 0);
    __builtin_amdgcn_s_setprio(0);
  };

  auto tile = [&](int kt, _Float16* Ac, _Float16* Bc, _Float16* An, _Float16* Bn) {
    const bool g1 = (kt + 1) < 32, g2 = (kt + 2) < 32;
    // phase 0: quadrant (m-pair0, n0)
    ldA(Ac, 0); ldB(Bc, 0);
    if (g1) { stageA(An, 64, kt + 1); stageA(An, 192, kt + 1); }
    SB0(); __builtin_amdgcn_s_barrier(); SB0();
    mm(0, 0);
    SB0(); __builtin_amdgcn_s_barrier(); SB0();
    // phase 1: quadrant (m-pair0, n1)
    ldB(Bc, 1);
    if (g2) { stageA(Ac, 0, kt + 2); stageA(Ac, 128, kt + 2); }
    SB0(); __builtin_amdgcn_s_barrier(); SB0();
    mm(0, 1);
    SB0(); __builtin_amdgcn_s_barrier(); SB0();
    // phase 2: quadrant (m-pair1, n1)
    ldA(Ac, 1);
    if (g2) { stageB(Bc, 0, kt + 2); stageB(Bc, 64, kt + 2); }
    SB0(); __builtin_amdgcn_s_barrier(); SB0();
    mm(1, 1);
    SB0(); __builtin_amdgcn_s_barrier(); SB0();
    // phase 3: quadrant (m-pair1, n0)
    if (g2) { stageB(Bc, 128, kt + 2); stageB(Bc, 192, kt + 2); }
    if (g2) { WAITV6(); } else { WAITV0(); }
    SB0(); __builtin_amdgcn_s_barrier(); SB0();
    mm(1, 0);
    SB0(); __builtin_amdgcn_s_barrier(); SB0();
  };

  // prologue: tile0 fully (8 chunks, oldest) + tile1's first 6 chunks
  stageA(As0, 0, 0); stageA(As0, 64, 0); stageA(As0, 128, 0); stageA(As0, 192, 0);
  stageB(Bs0, 0, 0); stageB(Bs0, 64, 0); stageB(Bs0, 128, 0); stageB(Bs0, 192, 0);
  stageA(As1, 0, 1); stageA(As1, 128, 1);
  stageB(Bs1, 0, 1); stageB(Bs1, 64, 1); stageB(Bs1, 128, 1); stageB(Bs1, 192, 1);
  WAITV6();
  SB0(); __builtin_amdgcn_s_barrier(); SB0();

  #pragma unroll 1
  for (int kt = 0; kt < 32; kt += 2) {
    tile(kt, As0, Bs0, As1, Bs1);
    tile(kt + 1, As1, Bs1, As0, Bs0);
  }

  // epilogue: transposed-C frag -> row-contiguous f16x4 stores (C pre-offset by m0*ldc + col base)
  #pragma unroll
  for (int s = 0; s < 4; ++s) {
    const size_t row = (size_t)(wm + s * 32 + l32);
    #pragma unroll
    for (int t = 0; t < 2; ++t)
      #pragma unroll
      for (int g = 0; g < 4; ++g) {
        const int col = wn + t * 32 + g * 8 + 4 * half;
        f16x4 o = { (_Float16)acc[s][t][4 * g + 0], (_Float16)acc[s][t][4 * g + 1],
                    (_Float16)acc[s][t][4 * g + 2], (_Float16)acc[s][t][4 * g + 3] };
        *(f16x4*)(C + row * ldc + col) = o;
      }
  }
}

// ---- fused QKV + V^T, 8-phase: 384 WGs x 512 thr, 1 WG/CU (128 KB LDS).
// Blocks 0..255: fused Q|K GEMM, C[4096][4096] = Hb . [Wq;Wk]^T (Wt rows 0..4095
// are contiguous), 256x256 tiles; n-tile < 8 -> Qb, else Kb (both ldc=2048).
// Blocks 256..383: V^T, C[2048][4096] = WvT . Hb^T, 256x256 tiles (short WGs last
// so they pack behind the long Q|K round).
__global__ __launch_bounds__(512, 2) void qkvv8(const _Float16* __restrict__ Hb,
                                                const _Float16* __restrict__ Wt,
                                                _Float16* __restrict__ Qb,
                                                _Float16* __restrict__ Kb,
                                                _Float16* __restrict__ Vtb) {
  __shared__ _Float16 S[65536];  // 128 KB
  const int id = blockIdx.x;
  if (id < 256) {
    const int m0 = (id >> 4) * 256, n0 = (id & 15) * 256;
    _Float16* C = (n0 < 2048 ? Qb + n0 : Kb + (n0 - 2048)) + (size_t)m0 * 2048;
    gemm256(Hb, Wt, C, 2048, m0, n0, S);
  } else {
    const int t = id - 256;
    const int m0 = (t >> 4) * 256, n0 = (t & 15) * 256;
    gemm256(Wt + (size_t)2 * 4194304, Hb, Vtb + (size_t)m0 * 4096 + n0, 4096, m0, n0, S);
  }
}

// ---- Wo GEMM: 128x128 tile, BK=64 (512 WGs, 2/CU) ----
__global__ __launch_bounds__(256) void gemm_wo(const _Float16* __restrict__ A,
                                               const _Float16* __restrict__ Bt,
                                               float* __restrict__ C) {
  __shared__ _Float16 S[16384];  // 32 KB
  const int t = blockIdx.x;
  gemm_tile<2, 2>(A, Bt, C, 2048, 2048, (t >> 4) * 128, (t & 15) * 128, S);
}

// ---- block-sparse attention (round-3 structure, V^T direct from GEMM) ----
__global__ __launch_bounds__(256) void attn(const _Float16* __restrict__ Qg,
                                            const _Float16* __restrict__ Kg,
                                            const _Float16* __restrict__ Vtg,
                                            _Float16* __restrict__ Og) {
  const int t = blockIdx.x, h = blockIdx.y, b = blockIdx.z;
  __shared__ _Float16 Qs[128 * 128];  // 32 KB
  __shared__ _Float16 Ks[64 * 128];   // 16 KB
  __shared__ _Float16 Vs[128 * 64];   // 16 KB
  const int tid = threadIdx.x;
  const int lane = tid & 63, w = tid >> 6, l16 = lane & 15, quad = lane >> 4;
  const int qbw = 2 * t + (w >> 1);
  const char* QsB = (const char*)Qs;
  const char* KsB = (const char*)Ks;
  const char* VsB = (const char*)Vs;

  #pragma unroll
  for (int p = 0; p < 8; ++p) {
    int o = p * 256 + tid, r = o >> 4, c = o & 15;
    gload_lds16(Qg + (size_t)(b * 2048 + t * 128 + r) * 2048 + h * 128 + ((c ^ (r & 15)) * 8),
                (char*)Qs + o * 16);
  }
  __builtin_amdgcn_s_waitcnt(0);
  __syncthreads();
  f16x8 qf[2][4];
  #pragma unroll
  for (int qc = 0; qc < 2; ++qc)
    #pragma unroll
    for (int ks = 0; ks < 4; ++ks)
      qf[qc][ks] = *(const f16x8*)(QsB + (w * 32 + qc * 16 + l16) * 256 +
                                   (((ks * 4 + quad) ^ l16) * 16));

  const float scale = 0.08838834764831845f;  // 1/sqrt(128)
  float m_[2] = {-1e30f, -1e30f}, l_[2] = {0.f, 0.f};
  f32x4 oacc[8][2];
  #pragma unroll
  for (int dt = 0; dt < 8; ++dt)
    #pragma unroll
    for (int qc = 0; qc < 2; ++qc) oacc[dt][qc] = (f32x4){0.f, 0.f, 0.f, 0.f};

  for (int jj = 0; jj < 6; ++jj) {
    const int j = 2 * t - 2 + jj;
    const int jc = j < 0 ? 0 : (j > 31 ? 31 : j);
    __syncthreads();
    #pragma unroll
    for (int p = 0; p < 4; ++p) {
      int o = p * 256 + tid, r = o >> 4, c = o & 15;
      gload_lds16(Kg + (size_t)(b * 2048 + jc * 64 + r) * 2048 + h * 128 + ((c ^ (r & 15)) * 8),
                  (char*)Ks + o * 16);
    }
    #pragma unroll
    for (int p = 0; p < 4; ++p) {
      int o = p * 256 + tid, d = o >> 3, c = o & 7;
      gload_lds16(Vtg + (size_t)(h * 128 + d) * 4096 + b * 2048 + jc * 64 + ((c ^ (d & 7)) * 8),
                  (char*)Vs + o * 16);
    }
    __builtin_amdgcn_s_waitcnt(0);
    __syncthreads();

    const bool valid = (j >= 0) && (j <= 31) && (j >= qbw - 2) && (j <= qbw + 2);
    if (valid) {
      f32x4 sc[4][2];
      #pragma unroll
      for (int kt = 0; kt < 4; ++kt)
        #pragma unroll
        for (int qc = 0; qc < 2; ++qc) sc[kt][qc] = (f32x4){0.f, 0.f, 0.f, 0.f};
      #pragma unroll
      for (int kt = 0; kt < 4; ++kt)
        #pragma unroll
        for (int ks = 0; ks < 4; ++ks) {
          f16x8 kf = *(const f16x8*)(KsB + (kt * 16 + l16) * 256 + (((ks * 4 + quad) ^ l16) * 16));
          #pragma unroll
          for (int qc = 0; qc < 2; ++qc)
            sc[kt][qc] = __builtin_amdgcn_mfma_f32_16x16x32_f16(kf, qf[qc][ks], sc[kt][qc], 0, 0, 0);
        }
      #pragma unroll
      for (int qc = 0; qc < 2; ++qc) {
        float mj = -1e30f;
        #pragma unroll
        for (int kt = 0; kt < 4; ++kt)
          #pragma unroll
          for (int r = 0; r < 4; ++r) {
            float v = sc[kt][qc][r] * scale;
            sc[kt][qc][r] = v;
            mj = fmaxf(mj, v);
          }
        mj = fmaxf(mj, __shfl_xor(mj, 16));
        mj = fmaxf(mj, __shfl_xor(mj, 32));
        const float mn = fmaxf(m_[qc], mj);
        const float alpha = __expf(m_[qc] - mn);
        float s_ = 0.f;
        #pragma unroll
        for (int kt = 0; kt < 4; ++kt)
          #pragma unroll
          for (int r = 0; r < 4; ++r) {
            float p = __expf(sc[kt][qc][r] - mn);
            sc[kt][qc][r] = p;
            s_ += p;
          }
        s_ += __shfl_xor(s_, 16);
        s_ += __shfl_xor(s_, 32);
        l_[qc] = l_[qc] * alpha + s_;
        m_[qc] = mn;
        #pragma unroll
        for (int dt = 0; dt < 8; ++dt) oacc[dt][qc] *= alpha;
      }
      #pragma unroll
      for (int kt = 0; kt < 4; ++kt) {
        f16x4 pb[2];
        #pragma unroll
        for (int qc = 0; qc < 2; ++qc)
          pb[qc] = (f16x4){ (_Float16)sc[kt][qc][0], (_Float16)sc[kt][qc][1],
                            (_Float16)sc[kt][qc][2], (_Float16)sc[kt][qc][3] };
        #pragma unroll
        for (int dt = 0; dt < 8; ++dt) {
          f16x4 vv = *(const f16x4*)(VsB + (dt * 16 + l16) * 128 +
                                     (((2 * kt + (quad >> 1)) ^ (l16 & 7)) * 16) + (quad & 1) * 8);
          #pragma unroll
          for (int qc = 0; qc < 2; ++qc)
            oacc[dt][qc] = __builtin_amdgcn_mfma_f32_16x16x16f16(vv, pb[qc], oacc[dt][qc], 0, 0, 0);
        }
      }
    }
  }

  #pragma unroll
  for (int qc = 0; qc < 2; ++qc) {
    const float pinv = 1.0f / l_[qc];
    const size_t orow = (size_t)(b * 2048 + t * 128 + w * 32 + qc * 16 + l16);
    #pragma unroll
    for (int dt = 0; dt < 8; ++dt) {
      f16x4 ov = { (_Float16)(oacc[dt][qc][0] * pinv), (_Float16)(oacc[dt][qc][1] * pinv),
                   (_Float16)(oacc[dt][qc][2] * pinv), (_Float16)(oacc[dt][qc][3] * pinv) };
      *(f16x4*)(Og + orow * 2048 + h * 128 + dt * 16 + quad * 4) = ov;
    }
  }
}

extern "C" void kernel_launch(void* const* d_in, const int* in_sizes, int n_in,
                              void* d_out, int out_size, void* d_ws, size_t ws_size,
                              hipStream_t stream) {
  const float* Hs = (const float*)d_in[0];
  const float* Wq = (const float*)d_in[1];
  const float* Wk = (const float*)d_in[2];
  const float* Wv = (const float*)d_in[3];
  const float* Wo = (const float*)d_in[4];
  _Float16* Hb  = (_Float16*)d_ws;          // H cast  [4096][2048]
  _Float16* Wt  = Hb  + 8388608;            // Wq/Wk/Wv/Wo^T  4 x [2048][2048]
  _Float16* Qb  = Wt  + 16777216;           // Q  [b*2048+s][h*128+d]
  _Float16* Kb  = Qb  + 8388608;            // K  [b*2048+s][h*128+d]
  _Float16* Vtb = Kb  + 8388608;            // V^T [h*128+d][b*2048+s]
  _Float16* Ob  = Vtb + 8388608;            // attn out [b*2048+s][h*128+d]
  float* out = (float*)d_out;

  prep<<<12288, 256, 0, stream>>>(Hs, Wq, Wk, Wv, Wo, Hb, Wt);
  qkvv8<<<384, 512, 0, stream>>>(Hb, Wt, Qb, Kb, Vtb);
  attn<<<dim3(16, 16, 2), 256, 0, stream>>>(Qb, Kb, Vtb, Ob);
  gemm_wo<<<512, 256, 0, stream>>>(Ob, Wt + (size_t)3 * 4194304, out);
}

// Round 2
// 341.025 us; speedup vs baseline: 1.0613x; 1.0613x over previous
//
#include <hip/hip_runtime.h>

typedef __attribute__((ext_vector_type(4))) float f32x4;
typedef __attribute__((ext_vector_type(16))) float f32x16;
typedef __attribute__((ext_vector_type(8))) _Float16 f16x8;
typedef __attribute__((ext_vector_type(4))) _Float16 f16x4;

__device__ __forceinline__ void gload_lds16(const void* g, void* l) {
  __builtin_amdgcn_global_load_lds((__attribute__((address_space(1))) void*)(g),
                                   (__attribute__((address_space(3))) void*)(l), 16, 0, 0);
}

#define BAR() asm volatile("s_barrier" ::: "memory")
#define WAITV6() asm volatile("s_waitcnt vmcnt(6)" ::: "memory")
#define WAITV0() asm volatile("s_waitcnt vmcnt(0)" ::: "memory")

// ---- fused prep: cast H fp32->fp16 (blocks 0..8191) + weight transpose-cast ----
__global__ __launch_bounds__(256) void prep(const float* __restrict__ Hs,
                                            const float* __restrict__ W0, const float* __restrict__ W1,
                                            const float* __restrict__ W2, const float* __restrict__ W3,
                                            _Float16* __restrict__ Hb, _Float16* __restrict__ Wt) {
  __shared__ _Float16 tile[64][65];
  const int bid = blockIdx.x, tid = threadIdx.x;
  if (bid < 8192) {
    int i = (bid * 256 + tid) * 4;
    float4 v = *(const float4*)(Hs + i);
    f16x4 o = { (_Float16)v.x, (_Float16)v.y, (_Float16)v.z, (_Float16)v.w };
    *(f16x4*)(Hb + i) = o;
    return;
  }
  const int t = bid - 8192;
  const int z = t >> 10, k0 = ((t >> 5) & 31) * 64, n0 = (t & 31) * 64;
  const float* W = z == 0 ? W0 : z == 1 ? W1 : z == 2 ? W2 : W3;
  _Float16* Wo_ = Wt + (size_t)z * (2048u * 2048u);
  #pragma unroll
  for (int p = 0; p < 4; ++p) {
    int o = p * 256 + tid, r = o >> 4, c = o & 15;
    float4 v = *(const float4*)(W + (size_t)(k0 + r) * 2048 + n0 + c * 4);
    tile[r][c * 4 + 0] = (_Float16)v.x;
    tile[r][c * 4 + 1] = (_Float16)v.y;
    tile[r][c * 4 + 2] = (_Float16)v.z;
    tile[r][c * 4 + 3] = (_Float16)v.w;
  }
  __syncthreads();
  #pragma unroll
  for (int p = 0; p < 2; ++p) {
    int o = p * 256 + tid, nl = o >> 3, c = o & 7;
    f16x8 u;
    #pragma unroll
    for (int i = 0; i < 8; ++i) u[i] = tile[c * 8 + i][nl];
    *(f16x8*)(Wo_ + (size_t)(n0 + nl) * 2048 + k0 + c * 8) = u;
  }
}

// ---- generic big-tile GEMM tile (serial schedule) — still used by gemm_wo ----
template <int SM, int SN, typename OutT>
__device__ __forceinline__ void gemm_tile(const _Float16* __restrict__ A,
                                          const _Float16* __restrict__ Bt,
                                          OutT* __restrict__ C,
                                          int K, int N, int m0, int n0, _Float16* S) {
  _Float16* As = S;                    // (SM*64) x 64
  _Float16* Bs = S + SM * 64 * 64;     // (SN*64) x 64
  const int tid = threadIdx.x;
  const int lane = tid & 63, w = tid >> 6, l32 = lane & 31, half = lane >> 5;
  const int wm = (w & 1) * SM * 32, wn = (w >> 1) * SN * 32;
  f32x16 acc[SM][SN];
  #pragma unroll
  for (int s = 0; s < SM; ++s)
    #pragma unroll
    for (int t = 0; t < SN; ++t) acc[s][t] = 0;

  for (int k0 = 0; k0 < K; k0 += 64) {
    __syncthreads();
    #pragma unroll
    for (int p = 0; p < SM * 2; ++p) {
      int o = p * 256 + tid, r = o >> 3, c = o & 7;
      gload_lds16(A + (size_t)(m0 + r) * K + k0 + ((c ^ (r & 7)) * 8), (char*)As + o * 16);
    }
    #pragma unroll
    for (int p = 0; p < SN * 2; ++p) {
      int o = p * 256 + tid, r = o >> 3, c = o & 7;
      gload_lds16(Bt + (size_t)(n0 + r) * K + k0 + ((c ^ (r & 7)) * 8), (char*)Bs + o * 16);
    }
    __builtin_amdgcn_s_waitcnt(0);
    __syncthreads();
    #pragma unroll
    for (int kk = 0; kk < 4; ++kk) {
      const int slot = ((2 * kk + half) ^ (l32 & 7)) * 8;
      f16x8 af[SM], bf[SN];
      #pragma unroll
      for (int s = 0; s < SM; ++s) af[s] = *(const f16x8*)(As + (wm + s * 32 + l32) * 64 + slot);
      #pragma unroll
      for (int t = 0; t < SN; ++t) bf[t] = *(const f16x8*)(Bs + (wn + t * 32 + l32) * 64 + slot);
      #pragma unroll
      for (int s = 0; s < SM; ++s)
        #pragma unroll
        for (int t = 0; t < SN; ++t)
          acc[s][t] = __builtin_amdgcn_mfma_f32_32x32x16_f16(bf[t], af[s], acc[s][t], 0, 0, 0);
    }
  }
  #pragma unroll
  for (int s = 0; s < SM; ++s) {
    const size_t row = (size_t)(m0 + wm + s * 32 + l32);
    #pragma unroll
    for (int t = 0; t < SN; ++t) {
      #pragma unroll
      for (int g = 0; g < 4; ++g) {
        const int col = n0 + wn + t * 32 + g * 8 + 4 * half;
        if constexpr (sizeof(OutT) == 2) {
          f16x4 o = { (_Float16)acc[s][t][4 * g + 0], (_Float16)acc[s][t][4 * g + 1],
                      (_Float16)acc[s][t][4 * g + 2], (_Float16)acc[s][t][4 * g + 3] };
          *(f16x4*)((_Float16*)C + row * N + col) = o;
        } else {
          f32x4 o = { acc[s][t][4 * g + 0], acc[s][t][4 * g + 1],
                      acc[s][t][4 * g + 2], acc[s][t][4 * g + 3] };
          *(f32x4*)((float*)C + row * N + col) = o;
        }
      }
    }
  }
}

// ---- 256x256 pipelined GEMM, overlap schedule.
// 512 thr = 8 waves (2M x 4N), wave tile 128x64, BK=64, K=2048 (32 tiles).
// LDS 128 KB double buffer. 3 barriers / K-tile; counted vmcnt(6); no sched_barrier.
// All fragment ds_reads issued up-front per cluster group; compiler's fine-grained
// lgkmcnt drains them UNDER the MFMA clusters (LDS/MFMA overlap).
// Hazard ledger (per tile t, cur=Ac/Bc, other=An):
//   ph0 stage An rows{64-127,192-255} (A t+1 pair1): rows last read in tile t-1, t-1's
//       end-barrier orders them. SAFE.
//   B1 (after mm(0,0)): drains af-pair0 reads -> stage Ac rows{0-63,128-191} (t+2 pair0).
//   B2 (after mm(0,1)): drains bf1 (bf0 drained at mm(0,0)) -> stage Bc all rows (t+2);
//       af-pair1 reads (rows 64-127,192-255 of Ac) disjoint from this tile's A stages.
//   vmcnt(6)+B3: per-wave drains 8 oldest = ALL of tile t+1; barrier publishes all
//       waves' LDS writes -> next tile's reads safe. Tail (no t+2): vmcnt(0).
__device__ __forceinline__ void gemm256(const _Float16* __restrict__ A,
                                        const _Float16* __restrict__ Bt,
                                        _Float16* __restrict__ C, int ldc,
                                        int m0, int n0, _Float16* S) {
  _Float16* const As0 = S;
  _Float16* const As1 = S + 16384;
  _Float16* const Bs0 = S + 32768;
  _Float16* const Bs1 = S + 49152;
  const int tid = (int)threadIdx.x;
  const int lane = tid & 63, w = tid >> 6, l32 = lane & 31, half = lane >> 5;
  const int wm = (w & 1) * 128, wn = (w >> 1) * 64;

  f32x16 acc[4][2];
  #pragma unroll
  for (int s = 0; s < 4; ++s)
    #pragma unroll
    for (int t = 0; t < 2; ++t) acc[s][t] = 0;

  f16x8 af[2][4];   // current m-pair fragments (reloaded pair0 -> pair1 mid-tile)
  f16x8 bf[2][4];   // both n-frags, live across the whole K-tile

  auto stageA = [&](_Float16* dst, int ar, int kt) {
    const int r = tid >> 3, c = tid & 7;
    gload_lds16(A + (size_t)(m0 + ar + r) * 2048 + kt * 64 + ((c ^ (r & 7)) << 3),
                (char*)dst + ar * 128 + tid * 16);
  };
  auto stageB = [&](_Float16* dst, int br, int kt) {
    const int r = tid >> 3, c = tid & 7;
    gload_lds16(Bt + (size_t)(n0 + br + r) * 2048 + kt * 64 + ((c ^ (r & 7)) << 3),
                (char*)dst + br * 128 + tid * 16);
  };
  auto ldA = [&](const _Float16* as, int p) {
    #pragma unroll
    for (int s2 = 0; s2 < 2; ++s2)
      #pragma unroll
      for (int kk = 0; kk < 4; ++kk)
        af[s2][kk] = *(const f16x8*)(as + (wm + p * 64 + s2 * 32 + l32) * 64 +
                                     (((2 * kk + half) ^ (l32 & 7)) << 3));
  };
  auto ldB = [&](const _Float16* bs, int q) {
    #pragma unroll
    for (int kk = 0; kk < 4; ++kk)
      bf[q][kk] = *(const f16x8*)(bs + (wn + q * 32 + l32) * 64 +
                                  (((2 * kk + half) ^ (l32 & 7)) << 3));
  };
  auto mm8 = [&](int sp, int q) {
    __builtin_amdgcn_s_setprio(1);
    #pragma unroll
    for (int kk = 0; kk < 4; ++kk)
      #pragma unroll
      for (int s2 = 0; s2 < 2; ++s2)
        acc[sp * 2 + s2][q] = __builtin_amdgcn_mfma_f32_32x32x16_f16(
            bf[q][kk], af[s2][kk], acc[sp * 2 + s2][q], 0, 0, 0);
    __builtin_amdgcn_s_setprio(0);
  };

  // prologue: tile0 fully (8 chunks, oldest) + tile1's first 6 chunks
  stageA(As0, 0, 0); stageA(As0, 64, 0); stageA(As0, 128, 0); stageA(As0, 192, 0);
  stageB(Bs0, 0, 0); stageB(Bs0, 64, 0); stageB(Bs0, 128, 0); stageB(Bs0, 192, 0);
  stageA(As1, 0, 1); stageA(As1, 128, 1);
  stageB(Bs1, 0, 1); stageB(Bs1, 64, 1); stageB(Bs1, 128, 1); stageB(Bs1, 192, 1);
  WAITV6();
  BAR();

  auto tile = [&](int kt, _Float16* Ac, _Float16* Bc, _Float16* An) {
    const bool g1 = (kt + 1) < 32, g2 = (kt + 2) < 32;
    ldA(Ac, 0);                 // af <- pair0 (8 ds_reads)
    ldB(Bc, 0); ldB(Bc, 1);     // bf (8 ds_reads)
    if (g1) { stageA(An, 64, kt + 1); stageA(An, 192, kt + 1); }
    mm8(0, 0);                  // drains af-pair0 + bf0
    BAR();                      // B1
    if (g2) { stageA(Ac, 0, kt + 2); stageA(Ac, 128, kt + 2); }
    mm8(0, 1);                  // drains bf1
    BAR();                      // B2
    ldA(Ac, 1);                 // af <- pair1 (8 ds_reads, rows disjoint from A stages)
    if (g2) { stageB(Bc, 0, kt + 2); stageB(Bc, 64, kt + 2);
              stageB(Bc, 128, kt + 2); stageB(Bc, 192, kt + 2); }
    mm8(1, 1);
    mm8(1, 0);                  // drains af-pair1
    if (g2) { WAITV6(); } else { WAITV0(); }
    BAR();                      // B3
  };

  #pragma unroll 1
  for (int kt = 0; kt < 32; kt += 2) {
    tile(kt, As0, Bs0, As1);
    tile(kt + 1, As1, Bs1, As0);
  }

  // epilogue: transposed-C frag -> row-contiguous f16x4 stores (C pre-offset)
  #pragma unroll
  for (int s = 0; s < 4; ++s) {
    const size_t row = (size_t)(wm + s * 32 + l32);
    #pragma unroll
    for (int t = 0; t < 2; ++t)
      #pragma unroll
      for (int g = 0; g < 4; ++g) {
        const int col = wn + t * 32 + g * 8 + 4 * half;
        f16x4 o = { (_Float16)acc[s][t][4 * g + 0], (_Float16)acc[s][t][4 * g + 1],
                    (_Float16)acc[s][t][4 * g + 2], (_Float16)acc[s][t][4 * g + 3] };
        *(f16x4*)(C + row * ldc + col) = o;
      }
  }
}

// ---- 128x256 pipelined GEMM (half-tile), same engine. 8 waves (2M x 4N),
// wave tile 64x64, acc 2x2. LDS 96 KB (subset of the 128 KB buffer).
// 2 barriers / K-tile: all reads drained by the two MFMA clusters, then barrier,
// then stage t+2 into current buffers, vmcnt(6), barrier.
__device__ __forceinline__ void gemm128(const _Float16* __restrict__ A,
                                        const _Float16* __restrict__ Bt,
                                        _Float16* __restrict__ C, int ldc,
                                        int m0, int n0, _Float16* S) {
  _Float16* const As0 = S;             // 128 x 64
  _Float16* const As1 = S + 8192;
  _Float16* const Bs0 = S + 16384;     // 256 x 64
  _Float16* const Bs1 = S + 32768;
  const int tid = (int)threadIdx.x;
  const int lane = tid & 63, w = tid >> 6, l32 = lane & 31, half = lane >> 5;
  const int wm = (w & 1) * 64, wn = (w >> 1) * 64;

  f32x16 acc[2][2];
  #pragma unroll
  for (int s = 0; s < 2; ++s)
    #pragma unroll
    for (int t = 0; t < 2; ++t) acc[s][t] = 0;

  f16x8 af[2][4], bf[2][4];

  auto stA = [&](_Float16* dst, int ar, int kt) {
    const int r = tid >> 3, c = tid & 7;
    gload_lds16(A + (size_t)(m0 + ar + r) * 2048 + kt * 64 + ((c ^ (r & 7)) << 3),
                (char*)dst + ar * 128 + tid * 16);
  };
  auto stB = [&](_Float16* dst, int br, int kt) {
    const int r = tid >> 3, c = tid & 7;
    gload_lds16(Bt + (size_t)(n0 + br + r) * 2048 + kt * 64 + ((c ^ (r & 7)) << 3),
                (char*)dst + br * 128 + tid * 16);
  };
  auto ldA_ = [&](const _Float16* as) {
    #pragma unroll
    for (int s2 = 0; s2 < 2; ++s2)
      #pragma unroll
      for (int kk = 0; kk < 4; ++kk)
        af[s2][kk] = *(const f16x8*)(as + (wm + s2 * 32 + l32) * 64 +
                                     (((2 * kk + half) ^ (l32 & 7)) << 3));
  };
  auto ldB_ = [&](const _Float16* bs, int q) {
    #pragma unroll
    for (int kk = 0; kk < 4; ++kk)
      bf[q][kk] = *(const f16x8*)(bs + (wn + q * 32 + l32) * 64 +
                                  (((2 * kk + half) ^ (l32 & 7)) << 3));
  };
  auto mmq = [&](int q) {
    __builtin_amdgcn_s_setprio(1);
    #pragma unroll
    for (int kk = 0; kk < 4; ++kk)
      #pragma unroll
      for (int s2 = 0; s2 < 2; ++s2)
        acc[s2][q] = __builtin_amdgcn_mfma_f32_32x32x16_f16(
            bf[q][kk], af[s2][kk], acc[s2][q], 0, 0, 0);
    __builtin_amdgcn_s_setprio(0);
  };

  // prologue: tile0 (6 chunks, oldest) + tile1 (6 chunks)
  stA(As0, 0, 0); stA(As0, 64, 0);
  stB(Bs0, 0, 0); stB(Bs0, 64, 0); stB(Bs0, 128, 0); stB(Bs0, 192, 0);
  stA(As1, 0, 1); stA(As1, 64, 1);
  stB(Bs1, 0, 1); stB(Bs1, 64, 1); stB(Bs1, 128, 1); stB(Bs1, 192, 1);
  WAITV6();
  BAR();

  auto tile = [&](int kt, _Float16* Ac, _Float16* Bc) {
    const bool g2 = (kt + 2) < 32;
    ldA_(Ac); ldB_(Bc, 0); ldB_(Bc, 1);   // 16 ds_reads
    mmq(0);                                // drains af + bf0
    mmq(1);                                // drains bf1
    BAR();                                 // all waves' reads done
    if (g2) {
      stA(Ac, 0, kt + 2); stA(Ac, 64, kt + 2);
      stB(Bc, 0, kt + 2); stB(Bc, 64, kt + 2); stB(Bc, 128, kt + 2); stB(Bc, 192, kt + 2);
      WAITV6();                            // drains tile t+1's 6 chunks
    } else {
      WAITV0();
    }
    BAR();
  };

  #pragma unroll 1
  for (int kt = 0; kt < 32; kt += 2) {
    tile(kt, As0, Bs0);
    tile(kt + 1, As1, Bs1);
  }

  #pragma unroll
  for (int s = 0; s < 2; ++s) {
    const size_t row = (size_t)(wm + s * 32 + l32);
    #pragma unroll
    for (int t = 0; t < 2; ++t)
      #pragma unroll
      for (int g = 0; g < 4; ++g) {
        const int col = wn + t * 32 + g * 8 + 4 * half;
        f16x4 o = { (_Float16)acc[s][t][4 * g + 0], (_Float16)acc[s][t][4 * g + 1],
                    (_Float16)acc[s][t][4 * g + 2], (_Float16)acc[s][t][4 * g + 3] };
        *(f16x4*)(C + row * ldc + col) = o;
      }
  }
}

// ---- fused QKV + V^T: 256 WGs x 512 thr, 1 WG/CU, perfectly balanced.
// Every WG: one 256x256 Q|K tile (C[4096][4096] = Hb . [Wq;Wk]^T) then one
// 128x256 V^T half-tile (C[2048][4096] = WvT . Hb^T). Uniform 1.5 tiles/CU.
__global__ __launch_bounds__(512, 2) void qkvv3(const _Float16* __restrict__ Hb,
                                                const _Float16* __restrict__ Wt,
                                                _Float16* __restrict__ Qb,
                                                _Float16* __restrict__ Kb,
                                                _Float16* __restrict__ Vtb) {
  __shared__ _Float16 S[65536];  // 128 KB
  const int id = blockIdx.x;
  {
    const int m0 = (id >> 4) * 256, n0 = (id & 15) * 256;
    _Float16* Cq = (n0 < 2048 ? Qb + n0 : Kb + (n0 - 2048)) + (size_t)m0 * 2048;
    gemm256(Hb, Wt, Cq, 2048, m0, n0, S);
  }
  WAITV0();   // quiesce vmem before the next part's vmcnt ledger starts
  BAR();
  {
    const int m0 = (id >> 4) * 128, n0 = (id & 15) * 256;
    gemm128(Wt + (size_t)2 * 4194304, Hb, Vtb + (size_t)m0 * 4096 + n0, 4096, m0, n0, S);
  }
}

// ---- Wo GEMM: 128x128 tile, BK=64 (512 WGs, 2/CU) ----
__global__ __launch_bounds__(256) void gemm_wo(const _Float16* __restrict__ A,
                                               const _Float16* __restrict__ Bt,
                                               float* __restrict__ C) {
  __shared__ _Float16 S[16384];  // 32 KB
  const int t = blockIdx.x;
  gemm_tile<2, 2>(A, Bt, C, 2048, 2048, (t >> 4) * 128, (t & 15) * 128, S);
}

// ---- block-sparse attention (round-3 structure, V^T direct from GEMM) ----
__global__ __launch_bounds__(256) void attn(const _Float16* __restrict__ Qg,
                                            const _Float16* __restrict__ Kg,
                                            const _Float16* __restrict__ Vtg,
                                            _Float16* __restrict__ Og) {
  const int t = blockIdx.x, h = blockIdx.y, b = blockIdx.z;
  __shared__ _Float16 Qs[128 * 128];  // 32 KB
  __shared__ _Float16 Ks[64 * 128];   // 16 KB
  __shared__ _Float16 Vs[128 * 64];   // 16 KB
  const int tid = threadIdx.x;
  const int lane = tid & 63, w = tid >> 6, l16 = lane & 15, quad = lane >> 4;
  const int qbw = 2 * t + (w >> 1);
  const char* QsB = (const char*)Qs;
  const char* KsB = (const char*)Ks;
  const char* VsB = (const char*)Vs;

  #pragma unroll
  for (int p = 0; p < 8; ++p) {
    int o = p * 256 + tid, r = o >> 4, c = o & 15;
    gload_lds16(Qg + (size_t)(b * 2048 + t * 128 + r) * 2048 + h * 128 + ((c ^ (r & 15)) * 8),
                (char*)Qs + o * 16);
  }
  __builtin_amdgcn_s_waitcnt(0);
  __syncthreads();
  f16x8 qf[2][4];
  #pragma unroll
  for (int qc = 0; qc < 2; ++qc)
    #pragma unroll
    for (int ks = 0; ks < 4; ++ks)
      qf[qc][ks] = *(const f16x8*)(QsB + (w * 32 + qc * 16 + l16) * 256 +
                                   (((ks * 4 + quad) ^ l16) * 16));

  const float scale = 0.08838834764831845f;  // 1/sqrt(128)
  float m_[2] = {-1e30f, -1e30f}, l_[2] = {0.f, 0.f};
  f32x4 oacc[8][2];
  #pragma unroll
  for (int dt = 0; dt < 8; ++dt)
    #pragma unroll
    for (int qc = 0; qc < 2; ++qc) oacc[dt][qc] = (f32x4){0.f, 0.f, 0.f, 0.f};

  for (int jj = 0; jj < 6; ++jj) {
    const int j = 2 * t - 2 + jj;
    const int jc = j < 0 ? 0 : (j > 31 ? 31 : j);
    __syncthreads();
    #pragma unroll
    for (int p = 0; p < 4; ++p) {
      int o = p * 256 + tid, r = o >> 4, c = o & 15;
      gload_lds16(Kg + (size_t)(b * 2048 + jc * 64 + r) * 2048 + h * 128 + ((c ^ (r & 15)) * 8),
                  (char*)Ks + o * 16);
    }
    #pragma unroll
    for (int p = 0; p < 4; ++p) {
      int o = p * 256 + tid, d = o >> 3, c = o & 7;
      gload_lds16(Vtg + (size_t)(h * 128 + d) * 4096 + b * 2048 + jc * 64 + ((c ^ (d & 7)) * 8),
                  (char*)Vs + o * 16);
    }
    __builtin_amdgcn_s_waitcnt(0);
    __syncthreads();

    const bool valid = (j >= 0) && (j <= 31) && (j >= qbw - 2) && (j <= qbw + 2);
    if (valid) {
      f32x4 sc[4][2];
      #pragma unroll
      for (int kt = 0; kt < 4; ++kt)
        #pragma unroll
        for (int qc = 0; qc < 2; ++qc) sc[kt][qc] = (f32x4){0.f, 0.f, 0.f, 0.f};
      #pragma unroll
      for (int kt = 0; kt < 4; ++kt)
        #pragma unroll
        for (int ks = 0; ks < 4; ++ks) {
          f16x8 kf = *(const f16x8*)(KsB + (kt * 16 + l16) * 256 + (((ks * 4 + quad) ^ l16) * 16));
          #pragma unroll
          for (int qc = 0; qc < 2; ++qc)
            sc[kt][qc] = __builtin_amdgcn_mfma_f32_16x16x32_f16(kf, qf[qc][ks], sc[kt][qc], 0, 0, 0);
        }
      #pragma unroll
      for (int qc = 0; qc < 2; ++qc) {
        float mj = -1e30f;
        #pragma unroll
        for (int kt = 0; kt < 4; ++kt)
          #pragma unroll
          for (int r = 0; r < 4; ++r) {
            float v = sc[kt][qc][r] * scale;
            sc[kt][qc][r] = v;
            mj = fmaxf(mj, v);
          }
        mj = fmaxf(mj, __shfl_xor(mj, 16));
        mj = fmaxf(mj, __shfl_xor(mj, 32));
        const float mn = fmaxf(m_[qc], mj);
        const float alpha = __expf(m_[qc] - mn);
        float s_ = 0.f;
        #pragma unroll
        for (int kt = 0; kt < 4; ++kt)
          #pragma unroll
          for (int r = 0; r < 4; ++r) {
            float p = __expf(sc[kt][qc][r] - mn);
            sc[kt][qc][r] = p;
            s_ += p;
          }
        s_ += __shfl_xor(s_, 16);
        s_ += __shfl_xor(s_, 32);
        l_[qc] = l_[qc] * alpha + s_;
        m_[qc] = mn;
        #pragma unroll
        for (int dt = 0; dt < 8; ++dt) oacc[dt][qc] *= alpha;
      }
      #pragma unroll
      for (int kt = 0; kt < 4; ++kt) {
        f16x4 pb[2];
        #pragma unroll
        for (int qc = 0; qc < 2; ++qc)
          pb[qc] = (f16x4){ (_Float16)sc[kt][qc][0], (_Float16)sc[kt][qc][1],
                            (_Float16)sc[kt][qc][2], (_Float16)sc[kt][qc][3] };
        #pragma unroll
        for (int dt = 0; dt < 8; ++dt) {
          f16x4 vv = *(const f16x4*)(VsB + (dt * 16 + l16) * 128 +
                                     (((2 * kt + (quad >> 1)) ^ (l16 & 7)) * 16) + (quad & 1) * 8);
          #pragma unroll
          for (int qc = 0; qc < 2; ++qc)
            oacc[dt][qc] = __builtin_amdgcn_mfma_f32_16x16x16f16(vv, pb[qc], oacc[dt][qc], 0, 0, 0);
        }
      }
    }
  }

  #pragma unroll
  for (int qc = 0; qc < 2; ++qc) {
    const float pinv = 1.0f / l_[qc];
    const size_t orow = (size_t)(b * 2048 + t * 128 + w * 32 + qc * 16 + l16);
    #pragma unroll
    for (int dt = 0; dt < 8; ++dt) {
      f16x4 ov = { (_Float16)(oacc[dt][qc][0] * pinv), (_Float16)(oacc[dt][qc][1] * pinv),
                   (_Float16)(oacc[dt][qc][2] * pinv), (_Float16)(oacc[dt][qc][3] * pinv) };
      *(f16x4*)(Og + orow * 2048 + h * 128 + dt * 16 + quad * 4) = ov;
    }
  }
}

extern "C" void kernel_launch(void* const* d_in, const int* in_sizes, int n_in,
                              void* d_out, int out_size, void* d_ws, size_t ws_size,
                              hipStream_t stream) {
  const float* Hs = (const float*)d_in[0];
  const float* Wq = (const float*)d_in[1];
  const float* Wk = (const float*)d_in[2];
  const float* Wv = (const float*)d_in[3];
  const float* Wo = (const float*)d_in[4];
  _Float16* Hb  = (_Float16*)d_ws;          // H cast  [4096][2048]
  _Float16* Wt  = Hb  + 8388608;            // Wq/Wk/Wv/Wo^T  4 x [2048][2048]
  _Float16* Qb  = Wt  + 16777216;           // Q  [b*2048+s][h*128+d]
  _Float16* Kb  = Qb  + 8388608;            // K  [b*2048+s][h*128+d]
  _Float16* Vtb = Kb  + 8388608;            // V^T [h*128+d][b*2048+s]
  _Float16* Ob  = Vtb + 8388608;            // attn out [b*2048+s][h*128+d]
  float* out = (float*)d_out;

  prep<<<12288, 256, 0, stream>>>(Hs, Wq, Wk, Wv, Wo, Hb, Wt);
  qkvv3<<<256, 512, 0, stream>>>(Hb, Wt, Qb, Kb, Vtb);
  attn<<<dim3(16, 16, 2), 256, 0, stream>>>(Qb, Kb, Vtb, Ob);
  gemm_wo<<<512, 256, 0, stream>>>(Ob, Wt + (size_t)3 * 4194304, out);
}